// Round 9
// baseline (636.292 us; speedup 1.0000x reference)
//
#include <hip/hip_runtime.h>

#define BIG_NEG_F (-4294967296.0f)

__device__ __forceinline__ float wave_sum(float v) {
#pragma unroll
    for (int m = 32; m; m >>= 1) v += __shfl_xor(v, m, 64);
    return v;
}
__device__ __forceinline__ float wave_max(float v) {
#pragma unroll
    for (int m = 32; m; m >>= 1) v = fmaxf(v, __shfl_xor(v, m, 64));
    return v;
}

// Fused: detect mask layout (u8/i32/i64), normalize this row's bit, x = seq*keep, q = ln1(x).
__global__ __launch_bounds__(256) void prep_ln_kernel(const float* __restrict__ seq,
                                                      const unsigned char* __restrict__ mraw,
                                                      unsigned char* __restrict__ mout,
                                                      float* __restrict__ X, float* __restrict__ Q,
                                                      const float* __restrict__ g,
                                                      const float* __restrict__ be) {
    __shared__ int flags[2];
    __shared__ float ws[8];
    int row = blockIdx.x, tid = threadIdx.x;
    if (tid == 0) { flags[0] = 0; flags[1] = 0; }
    __syncthreads();
    for (int i = tid; i < 2048; i += 256) {
        if (mraw[i]) {
            if (i & 3) atomicOr(&flags[0], 1);
            else if (i & 4) atomicOr(&flags[1], 1);
        }
    }
    __syncthreads();
    int mode = flags[0] ? 0 : (flags[1] ? 1 : 2);
    unsigned char mrow = (mode == 0) ? mraw[row] : (mode == 1) ? mraw[row * 4] : mraw[row * 8];
    if (tid == 0) mout[row] = mrow ? 1 : 0;
    int idx = row * 256 + tid;
    int w = tid >> 6, lane = tid & 63;
    float v = mrow ? 0.f : seq[idx];
    X[idx] = v;
    float s = wave_sum(v);
    if (lane == 0) ws[w] = s;
    __syncthreads();
    float mean = (ws[0] + ws[1] + ws[2] + ws[3]) * (1.f / 256.f);
    float d = v - mean;
    float s2 = wave_sum(d * d);
    if (lane == 0) ws[4 + w] = s2;
    __syncthreads();
    float var = (ws[4] + ws[5] + ws[6] + ws[7]) * (1.f / 256.f);
    Q[idx] = d / sqrtf(var + 1e-8f) * g[tid] + be[tid];
}

// row layernorm over H=256
__global__ __launch_bounds__(256) void ln_kernel(const float* __restrict__ X, float* __restrict__ Y,
                                                 const float* __restrict__ g,
                                                 const float* __restrict__ be) {
    __shared__ float ws[8];
    int row = blockIdx.x, tid = threadIdx.x;
    int idx = row * 256 + tid;
    int w = tid >> 6, lane = tid & 63;
    float v = X[idx];
    float s = wave_sum(v);
    if (lane == 0) ws[w] = s;
    __syncthreads();
    float mean = (ws[0] + ws[1] + ws[2] + ws[3]) * (1.f / 256.f);
    float d = v - mean;
    float s2 = wave_sum(d * d);
    if (lane == 0) ws[4 + w] = s2;
    __syncthreads();
    float var = (ws[4] + ws[5] + ws[6] + ws[7]) * (1.f / 256.f);
    Y[idx] = d / sqrtf(var + 1e-8f) * g[tid] + be[tid];
}

struct GemmJob {
    const float* A; const float* W; const float* bias; const float* pos; float* C;
};

// 64x64 tile, 4x4/thread, BK=32 — QKV triple dispatch.
__global__ __launch_bounds__(256) void gemm64_kernel(GemmJob j0, GemmJob j1, GemmJob j2) {
    GemmJob J = (blockIdx.z == 0) ? j0 : (blockIdx.z == 1 ? j1 : j2);
    __shared__ float AsT[32][68];
    __shared__ float WsT[32][68];
    int tid = threadIdx.x;
    int n0 = blockIdx.x * 64, m0 = blockIdx.y * 64;
    int r = tid >> 4, c = tid & 15;
    int li = tid >> 2, lk = (tid & 3) * 8;
    float acc[4][4] = {};
    for (int k0 = 0; k0 < 256; k0 += 32) {
        float4 a0 = *(const float4*)(J.A + (m0 + li) * 256 + k0 + lk);
        float4 a1 = *(const float4*)(J.A + (m0 + li) * 256 + k0 + lk + 4);
        AsT[lk + 0][li] = a0.x; AsT[lk + 1][li] = a0.y; AsT[lk + 2][li] = a0.z; AsT[lk + 3][li] = a0.w;
        AsT[lk + 4][li] = a1.x; AsT[lk + 5][li] = a1.y; AsT[lk + 6][li] = a1.z; AsT[lk + 7][li] = a1.w;
        float4 w0 = *(const float4*)(J.W + (n0 + li) * 256 + k0 + lk);
        float4 w1 = *(const float4*)(J.W + (n0 + li) * 256 + k0 + lk + 4);
        WsT[lk + 0][li] = w0.x; WsT[lk + 1][li] = w0.y; WsT[lk + 2][li] = w0.z; WsT[lk + 3][li] = w0.w;
        WsT[lk + 4][li] = w1.x; WsT[lk + 5][li] = w1.y; WsT[lk + 6][li] = w1.z; WsT[lk + 7][li] = w1.w;
        __syncthreads();
#pragma unroll
        for (int kk = 0; kk < 32; ++kk) {
            float4 a = *(const float4*)&AsT[kk][r * 4];
            float4 bv = *(const float4*)&WsT[kk][c * 4];
            acc[0][0] += a.x * bv.x; acc[0][1] += a.x * bv.y; acc[0][2] += a.x * bv.z; acc[0][3] += a.x * bv.w;
            acc[1][0] += a.y * bv.x; acc[1][1] += a.y * bv.y; acc[1][2] += a.y * bv.z; acc[1][3] += a.y * bv.w;
            acc[2][0] += a.z * bv.x; acc[2][1] += a.z * bv.y; acc[2][2] += a.z * bv.z; acc[2][3] += a.z * bv.w;
            acc[3][0] += a.w * bv.x; acc[3][1] += a.w * bv.y; acc[3][2] += a.w * bv.z; acc[3][3] += a.w * bv.w;
        }
        __syncthreads();
    }
    int n = n0 + c * 4;
    float4 b4 = *(const float4*)(J.bias + n);
#pragma unroll
    for (int i = 0; i < 4; ++i) {
        int m = m0 + r * 4 + i;
        float4 v;
        v.x = acc[i][0] + b4.x; v.y = acc[i][1] + b4.y;
        v.z = acc[i][2] + b4.z; v.w = acc[i][3] + b4.w;
        if (J.pos) {
            float4 p4 = *(const float4*)(J.pos + (m & 255) * 256 + n);
            v.x += p4.x; v.y += p4.y; v.z += p4.z; v.w += p4.w;
        }
        *(float4*)(J.C + m * 256 + n) = v;
    }
}

// 32x32 tile, 2x2/thread — FFN GEMMs. relu / res / mask epilogue.
__global__ __launch_bounds__(256) void gemm32_kernel(const float* __restrict__ A,
                                                     const float* __restrict__ W,
                                                     const float* __restrict__ bias,
                                                     const float* __restrict__ res,
                                                     const unsigned char* __restrict__ maskm,
                                                     float* __restrict__ C, int relu) {
    __shared__ float AsT[32][34];
    __shared__ float WsT[32][34];
    int tid = threadIdx.x;
    int n0 = blockIdx.x * 32, m0 = blockIdx.y * 32;
    int r = tid >> 4, c = tid & 15;
    int li = tid >> 3, lk = (tid & 7) * 4;
    float acc00 = 0, acc01 = 0, acc10 = 0, acc11 = 0;
    for (int k0 = 0; k0 < 256; k0 += 32) {
        float4 av = *(const float4*)(A + (m0 + li) * 256 + k0 + lk);
        AsT[lk + 0][li] = av.x; AsT[lk + 1][li] = av.y; AsT[lk + 2][li] = av.z; AsT[lk + 3][li] = av.w;
        float4 wv = *(const float4*)(W + (n0 + li) * 256 + k0 + lk);
        WsT[lk + 0][li] = wv.x; WsT[lk + 1][li] = wv.y; WsT[lk + 2][li] = wv.z; WsT[lk + 3][li] = wv.w;
        __syncthreads();
#pragma unroll
        for (int kk = 0; kk < 32; ++kk) {
            float2 a = *(const float2*)&AsT[kk][r * 2];
            float2 b = *(const float2*)&WsT[kk][c * 2];
            acc00 += a.x * b.x; acc01 += a.x * b.y;
            acc10 += a.y * b.x; acc11 += a.y * b.y;
        }
        __syncthreads();
    }
    float accs[2][2] = {{acc00, acc01}, {acc10, acc11}};
#pragma unroll
    for (int i = 0; i < 2; ++i) {
        int m = m0 + r * 2 + i;
#pragma unroll
        for (int jj = 0; jj < 2; ++jj) {
            int n = n0 + c * 2 + jj;
            float v = accs[i][jj] + bias[n];
            if (relu) v = fmaxf(v, 0.f);
            if (res) v += res[m * 256 + n];
            if (maskm && maskm[m]) v = 0.f;
            C[m * 256 + n] = v;
        }
    }
}

// K1: T[qg][h][t] = sum_d Qb[qg][h*64+d] * tK[t][h*64+d].  64q x 64t tile, 4 heads seq.
__global__ __launch_bounds__(256) void qtk_kernel(const float* __restrict__ Qb,
                                                  const float* __restrict__ tK,
                                                  float* __restrict__ T) {
    __shared__ float QsT[32][68];
    __shared__ float TsT[32][68];
    int tid = threadIdx.x;
    int q0 = blockIdx.x * 64, t0 = blockIdx.y * 64;
    int r = tid >> 4, c = tid & 15;
    int li = tid >> 2, lk = (tid & 3) * 8;
    int tr = t0 + li; if (tr > 512) tr = 512;
    for (int h = 0; h < 4; ++h) {
        float acc[4][4] = {};
        for (int kc = 0; kc < 64; kc += 32) {
            float4 a0 = *(const float4*)(Qb + (q0 + li) * 256 + h * 64 + kc + lk);
            float4 a1 = *(const float4*)(Qb + (q0 + li) * 256 + h * 64 + kc + lk + 4);
            QsT[lk + 0][li] = a0.x; QsT[lk + 1][li] = a0.y; QsT[lk + 2][li] = a0.z; QsT[lk + 3][li] = a0.w;
            QsT[lk + 4][li] = a1.x; QsT[lk + 5][li] = a1.y; QsT[lk + 6][li] = a1.z; QsT[lk + 7][li] = a1.w;
            float4 b0 = *(const float4*)(tK + tr * 256 + h * 64 + kc + lk);
            float4 b1 = *(const float4*)(tK + tr * 256 + h * 64 + kc + lk + 4);
            TsT[lk + 0][li] = b0.x; TsT[lk + 1][li] = b0.y; TsT[lk + 2][li] = b0.z; TsT[lk + 3][li] = b0.w;
            TsT[lk + 4][li] = b1.x; TsT[lk + 5][li] = b1.y; TsT[lk + 6][li] = b1.z; TsT[lk + 7][li] = b1.w;
            __syncthreads();
#pragma unroll
            for (int kk = 0; kk < 32; ++kk) {
                float4 a = *(const float4*)&QsT[kk][r * 4];
                float4 bv = *(const float4*)&TsT[kk][c * 4];
                acc[0][0] += a.x * bv.x; acc[0][1] += a.x * bv.y; acc[0][2] += a.x * bv.z; acc[0][3] += a.x * bv.w;
                acc[1][0] += a.y * bv.x; acc[1][1] += a.y * bv.y; acc[1][2] += a.y * bv.z; acc[1][3] += a.y * bv.w;
                acc[2][0] += a.z * bv.x; acc[2][1] += a.z * bv.y; acc[2][2] += a.z * bv.z; acc[2][3] += a.z * bv.w;
                acc[3][0] += a.w * bv.x; acc[3][1] += a.w * bv.y; acc[3][2] += a.w * bv.z; acc[3][3] += a.w * bv.w;
            }
            __syncthreads();
        }
#pragma unroll
        for (int i = 0; i < 4; ++i)
#pragma unroll
            for (int j = 0; j < 4; ++j) {
                int t = t0 + c * 4 + j;
                if (t < 513) T[((size_t)(q0 + r * 4 + i) * 4 + h) * 513 + t] = acc[i][j];
            }
    }
}

// K2: per (b,h,16q): S = Q@K^T + T-gather, mask, softmax, G-histogram.
// Writes normalized [p(256) | G(544, zero-padded past 513)] rows of PG (stride 800).
__global__ __launch_bounds__(256) void score_kernel(const float* __restrict__ Qb,
                                                    const float* __restrict__ KpB,
                                                    const float* __restrict__ T,
                                                    const int* __restrict__ tm,
                                                    const unsigned char* __restrict__ mask,
                                                    float* __restrict__ PG) {
    int tid = threadIdx.x;
    int q0 = blockIdx.x * 16;             // within-b
    int bh = blockIdx.y, b = bh >> 2, h = bh & 3;
    __shared__ float Qs[16][68];
    __shared__ float Sl[16][264];
    __shared__ float Gl[4][544];
    __shared__ unsigned char mrow[16];
    {
        int li = tid >> 4, lk = tid & 15;
        *(float4*)&Qs[li][lk * 4] = *(const float4*)(Qb + (size_t)(b * 256 + q0 + li) * 256 + h * 64 + lk * 4);
    }
    if (tid < 16) mrow[tid] = mask[b * 256 + q0 + tid];
    __syncthreads();

    int k = tid;
    float4 kreg[16];
    const float* krow = KpB + (size_t)((b << 8) + k) * 256 + h * 64;
#pragma unroll
    for (int j = 0; j < 16; ++j) kreg[j] = *(const float4*)(krow + j * 4);
    float acc[16];
#pragma unroll
    for (int qq = 0; qq < 16; ++qq) acc[qq] = 0.f;
#pragma unroll
    for (int d4 = 0; d4 < 16; ++d4) {
        float4 kv = kreg[d4];
#pragma unroll
        for (int qq = 0; qq < 16; ++qq) {
            float4 q4 = *(const float4*)&Qs[qq][d4 * 4];
            acc[qq] += q4.x * kv.x + q4.y * kv.y + q4.z * kv.z + q4.w * kv.w;
        }
    }
    const int* tmcol = tm + (size_t)(b * 256 + q0) * 256 + k;
#pragma unroll
    for (int qq = 0; qq < 16; ++qq) {
        int qg = q0 + qq;
        int t = tmcol[qq * 256]; t = t < 0 ? 0 : (t > 512 ? 512 : t);
        float s = (acc[qq] + T[((size_t)(b * 256 + qg) * 4 + h) * 513 + t]) * 0.125f;
        if (k > qg || mrow[qq]) s = BIG_NEG_F;
        Sl[qq][k] = s;
    }
    __syncthreads();

    int w = tid >> 6, lane = tid & 63;
    float* pgB = PG + (size_t)bh * 256 * 800;
    for (int rr = 0; rr < 4; ++rr) {
        int qq = w * 4 + rr, qg = q0 + qq;
        float v0 = Sl[qq][lane], v1 = Sl[qq][lane + 64], v2 = Sl[qq][lane + 128], v3 = Sl[qq][lane + 192];
        float mx = wave_max(fmaxf(fmaxf(v0, v1), fmaxf(v2, v3)));
        float e0 = __expf(v0 - mx), e1 = __expf(v1 - mx), e2 = __expf(v2 - mx), e3 = __expf(v3 - mx);
        float inv = 1.f / wave_sum(e0 + e1 + e2 + e3);
        e0 *= inv; e1 *= inv; e2 *= inv; e3 *= inv;
        float* prow = pgB + (size_t)qg * 800;
        prow[lane] = e0; prow[lane + 64] = e1; prow[lane + 128] = e2; prow[lane + 192] = e3;
#pragma unroll
        for (int j = 0; j < 9; ++j) { int idx = lane + j * 64; if (idx < 544) Gl[w][idx] = 0.f; }
        const int* tq = tm + (size_t)(b * 256 + qg) * 256;
        {
            int ta = tq[lane], tb2 = tq[lane + 64], tc = tq[lane + 128], td = tq[lane + 192];
            ta = ta < 0 ? 0 : (ta > 512 ? 512 : ta);
            tb2 = tb2 < 0 ? 0 : (tb2 > 512 ? 512 : tb2);
            tc = tc < 0 ? 0 : (tc > 512 ? 512 : tc);
            td = td < 0 ? 0 : (td > 512 ? 512 : td);
            atomicAdd(&Gl[w][ta], e0);
            atomicAdd(&Gl[w][tb2], e1);
            atomicAdd(&Gl[w][tc], e2);
            atomicAdd(&Gl[w][td], e3);
        }
#pragma unroll
        for (int j = 0; j < 9; ++j) { int idx = lane + j * 64; if (idx < 544) prow[256 + idx] = Gl[w][idx]; }
    }
}

// K3: xn = qres + [p|G] @ [V ; tV ; 0pad]  (K=800). 32q x 64n per block.
__global__ __launch_bounds__(256) void outv_kernel(const float* __restrict__ PG,
                                                   const float* __restrict__ Vp,
                                                   const float* __restrict__ tV,
                                                   const float* __restrict__ qres,
                                                   float* __restrict__ xn) {
    int tid = threadIdx.x;
    int q0 = blockIdx.x * 32;
    int bh = blockIdx.y, b = bh >> 2, h = bh & 3;
    __shared__ float AsT[32][36];
    __shared__ float Bs[32][68];
    int liA = tid >> 3, lkA = (tid & 7) * 4;
    int liB = tid >> 3, lkB = (tid & 7) * 8;
    int q2 = tid & 15, cc = tid >> 4;
    float acc[2][4] = {};
    const float* Abase = PG + (size_t)bh * 256 * 800;
    for (int kc = 0; kc < 800; kc += 32) {
        float4 a4 = *(const float4*)(Abase + (size_t)(q0 + liA) * 800 + kc + lkA);
        AsT[lkA + 0][liA] = a4.x; AsT[lkA + 1][liA] = a4.y;
        AsT[lkA + 2][liA] = a4.z; AsT[lkA + 3][liA] = a4.w;
        int rrow = kc + liB;
        float4 b0, b1;
        if (rrow < 256) {
            const float* p = Vp + (size_t)((b << 8) + rrow) * 256 + h * 64 + lkB;
            b0 = *(const float4*)p; b1 = *(const float4*)(p + 4);
        } else if (rrow < 769) {
            const float* p = tV + (size_t)(rrow - 256) * 256 + h * 64 + lkB;
            b0 = *(const float4*)p; b1 = *(const float4*)(p + 4);
        } else {
            b0 = make_float4(0.f, 0.f, 0.f, 0.f); b1 = b0;
        }
        *(float4*)&Bs[liB][lkB] = b0;
        *(float4*)&Bs[liB][lkB + 4] = b1;
        __syncthreads();
#pragma unroll
        for (int kk = 0; kk < 32; ++kk) {
            float4 b4 = *(const float4*)&Bs[kk][cc * 4];
            float a0 = AsT[kk][q2], a1 = AsT[kk][q2 + 16];
            acc[0][0] += a0 * b4.x; acc[0][1] += a0 * b4.y; acc[0][2] += a0 * b4.z; acc[0][3] += a0 * b4.w;
            acc[1][0] += a1 * b4.x; acc[1][1] += a1 * b4.y; acc[1][2] += a1 * b4.z; acc[1][3] += a1 * b4.w;
        }
        __syncthreads();
    }
#pragma unroll
    for (int s = 0; s < 2; ++s) {
        int qg = b * 256 + q0 + q2 + s * 16;
        int col = h * 64 + cc * 4;
        float4 rv = *(const float4*)(qres + (size_t)qg * 256 + col);
        float4 o;
        o.x = acc[s][0] + rv.x; o.y = acc[s][1] + rv.y;
        o.z = acc[s][2] + rv.z; o.w = acc[s][3] + rv.w;
        *(float4*)(xn + (size_t)qg * 256 + col) = o;
    }
}

extern "C" void kernel_launch(void* const* d_in, const int* in_sizes, int n_in,
                              void* d_out, int out_size, void* d_ws, size_t ws_size,
                              hipStream_t stream) {
    const unsigned char* mask_raw = (const unsigned char*)d_in[0];
    const float* seq  = (const float*)d_in[1];
    const int*   tm   = (const int*)d_in[3];
    const float* Wq   = (const float*)d_in[5];
    const float* bq   = (const float*)d_in[6];
    const float* Wk   = (const float*)d_in[7];
    const float* bk   = (const float*)d_in[8];
    const float* Wv   = (const float*)d_in[9];
    const float* bv   = (const float*)d_in[10];
    const float* ln1g = (const float*)d_in[11];
    const float* ln1b = (const float*)d_in[12];
    const float* ln2g = (const float*)d_in[13];
    const float* ln2b = (const float*)d_in[14];
    const float* W1   = (const float*)d_in[15];
    const float* b1   = (const float*)d_in[16];
    const float* W2   = (const float*)d_in[17];
    const float* b2   = (const float*)d_in[18];
    const float* posK = (const float*)d_in[19];
    const float* posV = (const float*)d_in[20];
    const float* tK   = (const float*)d_in[21];
    const float* tV   = (const float*)d_in[22];
    const float* lnfg = (const float*)d_in[23];
    const float* lnfb = (const float*)d_in[24];

    const size_t NEL = 8 * 256 * 256;
    float* x   = (float*)d_ws;          // also xn (attn out + residual)
    float* q   = x   + NEL;             // ln1 output / attn residual
    float* Qb  = q   + NEL;
    float* KpB = Qb  + NEL;
    float* VpB = KpB + NEL;
    float* x2  = VpB + NEL;
    float* hb  = x2  + NEL;
    unsigned char* mask = (unsigned char*)(hb + NEL);   // 2048 B (4KB slot)
    float* T  = hb + NEL + 1024;                        // [2048][4][513] = 16.8 MB
    float* PG = T + (size_t)2048 * 4 * 513;             // [32][256][800] = 26.2 MB

    dim3 gQKV(4, 32, 3);
    dim3 gFFN(8, 64);
    dim3 gQTK(32, 9);
    dim3 gSC(16, 32);
    dim3 gOV(8, 32);

    prep_ln_kernel<<<2048, 256, 0, stream>>>(seq, mask_raw, mask, x, q, ln1g, ln1b);
    for (int blk = 0; blk < 2; ++blk) {
        int o1 = blk * 256, oW = blk * 256 * 256;
        GemmJob jq = {q, Wq + oW, bq + o1, nullptr, Qb};
        GemmJob jk = {x, Wk + oW, bk + o1, posK,    KpB};
        GemmJob jv = {x, Wv + oW, bv + o1, posV,    VpB};
        gemm64_kernel<<<gQKV, 256, 0, stream>>>(jq, jk, jv);
        qtk_kernel<<<gQTK, 256, 0, stream>>>(Qb, tK, T);
        score_kernel<<<gSC, 256, 0, stream>>>(Qb, KpB, T, tm, mask, PG);
        outv_kernel<<<gOV, 256, 0, stream>>>(PG, VpB, tV, q, x);
        ln_kernel<<<2048, 256, 0, stream>>>(x, x2, ln2g + o1, ln2b + o1);
        gemm32_kernel<<<gFFN, 256, 0, stream>>>(x2, W1 + oW, b1 + o1, nullptr, nullptr, hb, 1);
        gemm32_kernel<<<gFFN, 256, 0, stream>>>(hb, W2 + oW, b2 + o1, x2, mask, x, 0);
        if (blk == 0) ln_kernel<<<2048, 256, 0, stream>>>(x, q, ln1g + 256, ln1b + 256);
    }
    ln_kernel<<<2048, 256, 0, stream>>>(x, (float*)d_out, lnfg, lnfb);
}

// Round 10
// 396.534 us; speedup vs baseline: 1.6046x; 1.6046x over previous
//
#include <hip/hip_runtime.h>

#define BIG_NEG_F (-4294967296.0f)

__device__ __forceinline__ float wave_sum(float v) {
#pragma unroll
    for (int m = 32; m; m >>= 1) v += __shfl_xor(v, m, 64);
    return v;
}
__device__ __forceinline__ float wave_max(float v) {
#pragma unroll
    for (int m = 32; m; m >>= 1) v = fmaxf(v, __shfl_xor(v, m, 64));
    return v;
}

// Fused: detect mask layout (u8/i32/i64), normalize this row's bit, x = seq*keep, q = ln1(x).
__global__ __launch_bounds__(256) void prep_ln_kernel(const float* __restrict__ seq,
                                                      const unsigned char* __restrict__ mraw,
                                                      unsigned char* __restrict__ mout,
                                                      float* __restrict__ X, float* __restrict__ Q,
                                                      const float* __restrict__ g,
                                                      const float* __restrict__ be) {
    __shared__ int flags[2];
    __shared__ float ws[8];
    int row = blockIdx.x, tid = threadIdx.x;
    if (tid == 0) { flags[0] = 0; flags[1] = 0; }
    __syncthreads();
    for (int i = tid; i < 2048; i += 256) {
        if (mraw[i]) {
            if (i & 3) atomicOr(&flags[0], 1);
            else if (i & 4) atomicOr(&flags[1], 1);
        }
    }
    __syncthreads();
    int mode = flags[0] ? 0 : (flags[1] ? 1 : 2);
    unsigned char mrow = (mode == 0) ? mraw[row] : (mode == 1) ? mraw[row * 4] : mraw[row * 8];
    if (tid == 0) mout[row] = mrow ? 1 : 0;
    int idx = row * 256 + tid;
    int w = tid >> 6, lane = tid & 63;
    float v = mrow ? 0.f : seq[idx];
    X[idx] = v;
    float s = wave_sum(v);
    if (lane == 0) ws[w] = s;
    __syncthreads();
    float mean = (ws[0] + ws[1] + ws[2] + ws[3]) * (1.f / 256.f);
    float d = v - mean;
    float s2 = wave_sum(d * d);
    if (lane == 0) ws[4 + w] = s2;
    __syncthreads();
    float var = (ws[4] + ws[5] + ws[6] + ws[7]) * (1.f / 256.f);
    Q[idx] = d / sqrtf(var + 1e-8f) * g[tid] + be[tid];
}

// row layernorm over H=256
__global__ __launch_bounds__(256) void ln_kernel(const float* __restrict__ X, float* __restrict__ Y,
                                                 const float* __restrict__ g,
                                                 const float* __restrict__ be) {
    __shared__ float ws[8];
    int row = blockIdx.x, tid = threadIdx.x;
    int idx = row * 256 + tid;
    int w = tid >> 6, lane = tid & 63;
    float v = X[idx];
    float s = wave_sum(v);
    if (lane == 0) ws[w] = s;
    __syncthreads();
    float mean = (ws[0] + ws[1] + ws[2] + ws[3]) * (1.f / 256.f);
    float d = v - mean;
    float s2 = wave_sum(d * d);
    if (lane == 0) ws[4 + w] = s2;
    __syncthreads();
    float var = (ws[4] + ws[5] + ws[6] + ws[7]) * (1.f / 256.f);
    Y[idx] = d / sqrtf(var + 1e-8f) * g[tid] + be[tid];
}

struct GemmJob {
    const float* A; const float* W; const float* bias; const float* pos; float* C;
};

// 64x64 tile, 4x4/thread, BK=32, register-prefetched global loads — QKV triple dispatch.
__global__ __launch_bounds__(256) void gemm64_kernel(GemmJob j0, GemmJob j1, GemmJob j2) {
    GemmJob J = (blockIdx.z == 0) ? j0 : (blockIdx.z == 1 ? j1 : j2);
    __shared__ float AsT[32][68];
    __shared__ float WsT[32][68];
    int tid = threadIdx.x;
    int n0 = blockIdx.x * 64, m0 = blockIdx.y * 64;
    int r = tid >> 4, c = tid & 15;
    int li = tid >> 2, lk = (tid & 3) * 8;
    const float* Ap = J.A + (m0 + li) * 256 + lk;
    const float* Wp = J.W + (n0 + li) * 256 + lk;
    float acc[4][4] = {};
    float4 a0 = *(const float4*)(Ap);
    float4 a1 = *(const float4*)(Ap + 4);
    float4 w0 = *(const float4*)(Wp);
    float4 w1 = *(const float4*)(Wp + 4);
    for (int k0 = 0; k0 < 256; k0 += 32) {
        AsT[lk + 0][li] = a0.x; AsT[lk + 1][li] = a0.y; AsT[lk + 2][li] = a0.z; AsT[lk + 3][li] = a0.w;
        AsT[lk + 4][li] = a1.x; AsT[lk + 5][li] = a1.y; AsT[lk + 6][li] = a1.z; AsT[lk + 7][li] = a1.w;
        WsT[lk + 0][li] = w0.x; WsT[lk + 1][li] = w0.y; WsT[lk + 2][li] = w0.z; WsT[lk + 3][li] = w0.w;
        WsT[lk + 4][li] = w1.x; WsT[lk + 5][li] = w1.y; WsT[lk + 6][li] = w1.z; WsT[lk + 7][li] = w1.w;
        __syncthreads();
        if (k0 + 32 < 256) {          // prefetch next chunk while computing this one
            a0 = *(const float4*)(Ap + k0 + 32);
            a1 = *(const float4*)(Ap + k0 + 36);
            w0 = *(const float4*)(Wp + k0 + 32);
            w1 = *(const float4*)(Wp + k0 + 36);
        }
#pragma unroll
        for (int kk = 0; kk < 32; ++kk) {
            float4 a = *(const float4*)&AsT[kk][r * 4];
            float4 bv = *(const float4*)&WsT[kk][c * 4];
            acc[0][0] += a.x * bv.x; acc[0][1] += a.x * bv.y; acc[0][2] += a.x * bv.z; acc[0][3] += a.x * bv.w;
            acc[1][0] += a.y * bv.x; acc[1][1] += a.y * bv.y; acc[1][2] += a.y * bv.z; acc[1][3] += a.y * bv.w;
            acc[2][0] += a.z * bv.x; acc[2][1] += a.z * bv.y; acc[2][2] += a.z * bv.z; acc[2][3] += a.z * bv.w;
            acc[3][0] += a.w * bv.x; acc[3][1] += a.w * bv.y; acc[3][2] += a.w * bv.z; acc[3][3] += a.w * bv.w;
        }
        __syncthreads();
    }
    int n = n0 + c * 4;
    float4 b4 = *(const float4*)(J.bias + n);
#pragma unroll
    for (int i = 0; i < 4; ++i) {
        int m = m0 + r * 4 + i;
        float4 v;
        v.x = acc[i][0] + b4.x; v.y = acc[i][1] + b4.y;
        v.z = acc[i][2] + b4.z; v.w = acc[i][3] + b4.w;
        if (J.pos) {
            float4 p4 = *(const float4*)(J.pos + (m & 255) * 256 + n);
            v.x += p4.x; v.y += p4.y; v.z += p4.z; v.w += p4.w;
        }
        *(float4*)(J.C + m * 256 + n) = v;
    }
}

// 32x32 tile, 2x2/thread, prefetched — FFN GEMMs. relu / res / mask epilogue.
__global__ __launch_bounds__(256) void gemm32_kernel(const float* __restrict__ A,
                                                     const float* __restrict__ W,
                                                     const float* __restrict__ bias,
                                                     const float* __restrict__ res,
                                                     const unsigned char* __restrict__ maskm,
                                                     float* __restrict__ C, int relu) {
    __shared__ float AsT[32][34];
    __shared__ float WsT[32][34];
    int tid = threadIdx.x;
    int n0 = blockIdx.x * 32, m0 = blockIdx.y * 32;
    int r = tid >> 4, c = tid & 15;
    int li = tid >> 3, lk = (tid & 7) * 4;
    const float* Ap = A + (m0 + li) * 256 + lk;
    const float* Wp = W + (n0 + li) * 256 + lk;
    float acc00 = 0, acc01 = 0, acc10 = 0, acc11 = 0;
    float4 av = *(const float4*)(Ap);
    float4 wv = *(const float4*)(Wp);
    for (int k0 = 0; k0 < 256; k0 += 32) {
        AsT[lk + 0][li] = av.x; AsT[lk + 1][li] = av.y; AsT[lk + 2][li] = av.z; AsT[lk + 3][li] = av.w;
        WsT[lk + 0][li] = wv.x; WsT[lk + 1][li] = wv.y; WsT[lk + 2][li] = wv.z; WsT[lk + 3][li] = wv.w;
        __syncthreads();
        if (k0 + 32 < 256) {
            av = *(const float4*)(Ap + k0 + 32);
            wv = *(const float4*)(Wp + k0 + 32);
        }
#pragma unroll
        for (int kk = 0; kk < 32; ++kk) {
            float2 a = *(const float2*)&AsT[kk][r * 2];
            float2 b = *(const float2*)&WsT[kk][c * 2];
            acc00 += a.x * b.x; acc01 += a.x * b.y;
            acc10 += a.y * b.x; acc11 += a.y * b.y;
        }
        __syncthreads();
    }
    float accs[2][2] = {{acc00, acc01}, {acc10, acc11}};
#pragma unroll
    for (int i = 0; i < 2; ++i) {
        int m = m0 + r * 2 + i;
#pragma unroll
        for (int jj = 0; jj < 2; ++jj) {
            int n = n0 + c * 2 + jj;
            float v = accs[i][jj] + bias[n];
            if (relu) v = fmaxf(v, 0.f);
            if (res) v += res[m * 256 + n];
            if (maskm && maskm[m]) v = 0.f;
            C[m * 256 + n] = v;
        }
    }
}

// K1: T[qg][h][t] = sum_d Qb[qg][h*64+d] * tK[t][h*64+d].  64q x 64t tile, 4 heads seq.
__global__ __launch_bounds__(256) void qtk_kernel(const float* __restrict__ Qb,
                                                  const float* __restrict__ tK,
                                                  float* __restrict__ T) {
    __shared__ float QsT[32][68];
    __shared__ float TsT[32][68];
    int tid = threadIdx.x;
    int q0 = blockIdx.x * 64, t0 = blockIdx.y * 64;
    int r = tid >> 4, c = tid & 15;
    int li = tid >> 2, lk = (tid & 3) * 8;
    int tr = t0 + li; if (tr > 512) tr = 512;
    for (int h = 0; h < 4; ++h) {
        float acc[4][4] = {};
        for (int kc = 0; kc < 64; kc += 32) {
            float4 a0 = *(const float4*)(Qb + (q0 + li) * 256 + h * 64 + kc + lk);
            float4 a1 = *(const float4*)(Qb + (q0 + li) * 256 + h * 64 + kc + lk + 4);
            QsT[lk + 0][li] = a0.x; QsT[lk + 1][li] = a0.y; QsT[lk + 2][li] = a0.z; QsT[lk + 3][li] = a0.w;
            QsT[lk + 4][li] = a1.x; QsT[lk + 5][li] = a1.y; QsT[lk + 6][li] = a1.z; QsT[lk + 7][li] = a1.w;
            float4 b0 = *(const float4*)(tK + tr * 256 + h * 64 + kc + lk);
            float4 b1 = *(const float4*)(tK + tr * 256 + h * 64 + kc + lk + 4);
            TsT[lk + 0][li] = b0.x; TsT[lk + 1][li] = b0.y; TsT[lk + 2][li] = b0.z; TsT[lk + 3][li] = b0.w;
            TsT[lk + 4][li] = b1.x; TsT[lk + 5][li] = b1.y; TsT[lk + 6][li] = b1.z; TsT[lk + 7][li] = b1.w;
            __syncthreads();
#pragma unroll
            for (int kk = 0; kk < 32; ++kk) {
                float4 a = *(const float4*)&QsT[kk][r * 4];
                float4 bv = *(const float4*)&TsT[kk][c * 4];
                acc[0][0] += a.x * bv.x; acc[0][1] += a.x * bv.y; acc[0][2] += a.x * bv.z; acc[0][3] += a.x * bv.w;
                acc[1][0] += a.y * bv.x; acc[1][1] += a.y * bv.y; acc[1][2] += a.y * bv.z; acc[1][3] += a.y * bv.w;
                acc[2][0] += a.z * bv.x; acc[2][1] += a.z * bv.y; acc[2][2] += a.z * bv.z; acc[2][3] += a.z * bv.w;
                acc[3][0] += a.w * bv.x; acc[3][1] += a.w * bv.y; acc[3][2] += a.w * bv.z; acc[3][3] += a.w * bv.w;
            }
            __syncthreads();
        }
#pragma unroll
        for (int i = 0; i < 4; ++i)
#pragma unroll
            for (int j = 0; j < 4; ++j) {
                int t = t0 + c * 4 + j;
                if (t < 513) T[((size_t)(q0 + r * 4 + i) * 4 + h) * 513 + t] = acc[i][j];
            }
    }
}

// K2: per (b,h,16q): S = Q@K^T + T-gather, mask, softmax, G-histogram.
// K is STREAMED (1 float4 live at a time) — acc[16] only, no kreg array (r9 spilled at 256 VGPR).
__global__ __launch_bounds__(256) void score_kernel(const float* __restrict__ Qb,
                                                    const float* __restrict__ KpB,
                                                    const float* __restrict__ T,
                                                    const int* __restrict__ tm,
                                                    const unsigned char* __restrict__ mask,
                                                    float* __restrict__ PG) {
    int tid = threadIdx.x;
    int q0 = blockIdx.x * 16;
    int bh = blockIdx.y, b = bh >> 2, h = bh & 3;
    __shared__ float Qs[16][68];
    __shared__ float Sl[16][264];
    __shared__ float Gl[4][544];
    __shared__ unsigned char mrow[16];
    {
        int li = tid >> 4, lk = tid & 15;
        *(float4*)&Qs[li][lk * 4] = *(const float4*)(Qb + (size_t)(b * 256 + q0 + li) * 256 + h * 64 + lk * 4);
    }
    if (tid < 16) mrow[tid] = mask[b * 256 + q0 + tid];
    __syncthreads();

    int k = tid;
    const float* krow = KpB + (size_t)((b << 8) + k) * 256 + h * 64;
    float acc[16];
#pragma unroll
    for (int qq = 0; qq < 16; ++qq) acc[qq] = 0.f;
#pragma unroll 4
    for (int d4 = 0; d4 < 16; ++d4) {
        float4 kv = *(const float4*)(krow + d4 * 4);
#pragma unroll
        for (int qq = 0; qq < 16; ++qq) {
            float4 q4 = *(const float4*)&Qs[qq][d4 * 4];
            acc[qq] += q4.x * kv.x + q4.y * kv.y + q4.z * kv.z + q4.w * kv.w;
        }
    }
    const int* tmcol = tm + (size_t)(b * 256 + q0) * 256 + k;
#pragma unroll
    for (int qq = 0; qq < 16; ++qq) {
        int qg = q0 + qq;
        int t = tmcol[qq * 256]; t = t < 0 ? 0 : (t > 512 ? 512 : t);
        float s = (acc[qq] + T[((size_t)(b * 256 + qg) * 4 + h) * 513 + t]) * 0.125f;
        if (k > qg || mrow[qq]) s = BIG_NEG_F;
        Sl[qq][k] = s;
    }
    __syncthreads();

    int w = tid >> 6, lane = tid & 63;
    float* pgB = PG + (size_t)bh * 256 * 800;
    for (int rr = 0; rr < 4; ++rr) {
        int qq = w * 4 + rr, qg = q0 + qq;
        float v0 = Sl[qq][lane], v1 = Sl[qq][lane + 64], v2 = Sl[qq][lane + 128], v3 = Sl[qq][lane + 192];
        float mx = wave_max(fmaxf(fmaxf(v0, v1), fmaxf(v2, v3)));
        float e0 = __expf(v0 - mx), e1 = __expf(v1 - mx), e2 = __expf(v2 - mx), e3 = __expf(v3 - mx);
        float inv = 1.f / wave_sum(e0 + e1 + e2 + e3);
        e0 *= inv; e1 *= inv; e2 *= inv; e3 *= inv;
        float* prow = pgB + (size_t)qg * 800;
        prow[lane] = e0; prow[lane + 64] = e1; prow[lane + 128] = e2; prow[lane + 192] = e3;
#pragma unroll
        for (int j = 0; j < 9; ++j) { int idx = lane + j * 64; if (idx < 544) Gl[w][idx] = 0.f; }
        const int* tq = tm + (size_t)(b * 256 + qg) * 256;
        {
            int ta = tq[lane], tb2 = tq[lane + 64], tc = tq[lane + 128], td = tq[lane + 192];
            ta = ta < 0 ? 0 : (ta > 512 ? 512 : ta);
            tb2 = tb2 < 0 ? 0 : (tb2 > 512 ? 512 : tb2);
            tc = tc < 0 ? 0 : (tc > 512 ? 512 : tc);
            td = td < 0 ? 0 : (td > 512 ? 512 : td);
            atomicAdd(&Gl[w][ta], e0);
            atomicAdd(&Gl[w][tb2], e1);
            atomicAdd(&Gl[w][tc], e2);
            atomicAdd(&Gl[w][td], e3);
        }
#pragma unroll
        for (int j = 0; j < 9; ++j) { int idx = lane + j * 64; if (idx < 544) prow[256 + idx] = Gl[w][idx]; }
    }
}

// K3: xn = qres + [p|G] @ [V ; tV ; 0pad]  (K=800). 32q x 64n tile, 2x4/thread, grid 256.
__global__ __launch_bounds__(256) void outv_kernel(const float* __restrict__ PG,
                                                   const float* __restrict__ Vp,
                                                   const float* __restrict__ tV,
                                                   const float* __restrict__ qres,
                                                   float* __restrict__ xn) {
    int tid = threadIdx.x;
    int q0 = blockIdx.x * 32;
    int bh = blockIdx.y, b = bh >> 2, h = bh & 3;
    __shared__ float AsT[32][36];   // [k][q]
    __shared__ float Bs[32][68];    // [k][n]
    int r = tid >> 4, c = tid & 15;       // thread: 2 q-rows (r*2, r*2+1), 4 n-cols (c*4)
    int liA = tid >> 3, lkA = (tid & 7) * 4;
    int liB = tid >> 3, lkB = (tid & 7) * 8;
    const float* Abase = PG + (size_t)bh * 256 * 800 + (size_t)(q0 + liA) * 800 + lkA;
    float acc[2][4] = {};
    for (int kc = 0; kc < 800; kc += 32) {
        float4 a4 = *(const float4*)(Abase + kc);
        AsT[lkA + 0][liA] = a4.x; AsT[lkA + 1][liA] = a4.y;
        AsT[lkA + 2][liA] = a4.z; AsT[lkA + 3][liA] = a4.w;
        int rrow = kc + liB;
        float4 b0, b1;
        if (rrow < 256) {
            const float* p = Vp + (size_t)((b << 8) + rrow) * 256 + h * 64 + lkB;
            b0 = *(const float4*)p; b1 = *(const float4*)(p + 4);
        } else if (rrow < 769) {
            const float* p = tV + (size_t)(rrow - 256) * 256 + h * 64 + lkB;
            b0 = *(const float4*)p; b1 = *(const float4*)(p + 4);
        } else {
            b0 = make_float4(0.f, 0.f, 0.f, 0.f); b1 = b0;
        }
        *(float4*)&Bs[liB][lkB] = b0;
        *(float4*)&Bs[liB][lkB + 4] = b1;
        __syncthreads();
#pragma unroll
        for (int kk = 0; kk < 32; ++kk) {
            float2 a = *(const float2*)&AsT[kk][r * 2];
            float4 b4 = *(const float4*)&Bs[kk][c * 4];
            acc[0][0] += a.x * b4.x; acc[0][1] += a.x * b4.y; acc[0][2] += a.x * b4.z; acc[0][3] += a.x * b4.w;
            acc[1][0] += a.y * b4.x; acc[1][1] += a.y * b4.y; acc[1][2] += a.y * b4.z; acc[1][3] += a.y * b4.w;
        }
        __syncthreads();
    }
#pragma unroll
    for (int s = 0; s < 2; ++s) {
        int qg = b * 256 + q0 + r * 2 + s;
        int col = h * 64 + c * 4;
        float4 rv = *(const float4*)(qres + (size_t)qg * 256 + col);
        float4 o;
        o.x = acc[s][0] + rv.x; o.y = acc[s][1] + rv.y;
        o.z = acc[s][2] + rv.z; o.w = acc[s][3] + rv.w;
        *(float4*)(xn + (size_t)qg * 256 + col) = o;
    }
}

extern "C" void kernel_launch(void* const* d_in, const int* in_sizes, int n_in,
                              void* d_out, int out_size, void* d_ws, size_t ws_size,
                              hipStream_t stream) {
    const unsigned char* mask_raw = (const unsigned char*)d_in[0];
    const float* seq  = (const float*)d_in[1];
    const int*   tm   = (const int*)d_in[3];
    const float* Wq   = (const float*)d_in[5];
    const float* bq   = (const float*)d_in[6];
    const float* Wk   = (const float*)d_in[7];
    const float* bk   = (const float*)d_in[8];
    const float* Wv   = (const float*)d_in[9];
    const float* bv   = (const float*)d_in[10];
    const float* ln1g = (const float*)d_in[11];
    const float* ln1b = (const float*)d_in[12];
    const float* ln2g = (const float*)d_in[13];
    const float* ln2b = (const float*)d_in[14];
    const float* W1   = (const float*)d_in[15];
    const float* b1   = (const float*)d_in[16];
    const float* W2   = (const float*)d_in[17];
    const float* b2   = (const float*)d_in[18];
    const float* posK = (const float*)d_in[19];
    const float* posV = (const float*)d_in[20];
    const float* tK   = (const float*)d_in[21];
    const float* tV   = (const float*)d_in[22];
    const float* lnfg = (const float*)d_in[23];
    const float* lnfb = (const float*)d_in[24];

    const size_t NEL = 8 * 256 * 256;
    float* x   = (float*)d_ws;
    float* q   = x   + NEL;
    float* Qb  = q   + NEL;
    float* KpB = Qb  + NEL;
    float* VpB = KpB + NEL;
    float* x2  = VpB + NEL;
    float* hb  = x2  + NEL;
    unsigned char* mask = (unsigned char*)(hb + NEL);
    float* T  = hb + NEL + 1024;                        // [2048][4][513]
    float* PG = T + (size_t)2048 * 4 * 513;             // [32][256][800]

    dim3 gQKV(4, 32, 3);
    dim3 gFFN(8, 64);
    dim3 gQTK(32, 9);
    dim3 gSC(16, 32);
    dim3 gOV(8, 32);

    prep_ln_kernel<<<2048, 256, 0, stream>>>(seq, mask_raw, mask, x, q, ln1g, ln1b);
    for (int blk = 0; blk < 2; ++blk) {
        int o1 = blk * 256, oW = blk * 256 * 256;
        GemmJob jq = {q, Wq + oW, bq + o1, nullptr, Qb};
        GemmJob jk = {x, Wk + oW, bk + o1, posK,    KpB};
        GemmJob jv = {x, Wv + oW, bv + o1, posV,    VpB};
        gemm64_kernel<<<gQKV, 256, 0, stream>>>(jq, jk, jv);
        qtk_kernel<<<gQTK, 256, 0, stream>>>(Qb, tK, T);
        score_kernel<<<gSC, 256, 0, stream>>>(Qb, KpB, T, tm, mask, PG);
        outv_kernel<<<gOV, 256, 0, stream>>>(PG, VpB, tV, q, x);
        ln_kernel<<<2048, 256, 0, stream>>>(x, x2, ln2g + o1, ln2b + o1);
        gemm32_kernel<<<gFFN, 256, 0, stream>>>(x2, W1 + oW, b1 + o1, nullptr, nullptr, hb, 1);
        gemm32_kernel<<<gFFN, 256, 0, stream>>>(hb, W2 + oW, b2 + o1, x2, mask, x, 0);
        if (blk == 0) ln_kernel<<<2048, 256, 0, stream>>>(x, q, ln1g + 256, ln1b + 256);
    }
    ln_kernel<<<2048, 256, 0, stream>>>(x, (float*)d_out, lnfg, lnfb);
}

// Round 11
// 383.288 us; speedup vs baseline: 1.6601x; 1.0346x over previous
//
#include <hip/hip_runtime.h>

#define BIG_NEG_F (-4294967296.0f)

__device__ __forceinline__ float wave_sum(float v) {
#pragma unroll
    for (int m = 32; m; m >>= 1) v += __shfl_xor(v, m, 64);
    return v;
}
__device__ __forceinline__ float wave_max(float v) {
#pragma unroll
    for (int m = 32; m; m >>= 1) v = fmaxf(v, __shfl_xor(v, m, 64));
    return v;
}

// Fused: detect mask layout (u8/i32/i64), normalize this row's bit, x = seq*keep, q = ln1(x).
__global__ __launch_bounds__(256) void prep_ln_kernel(const float* __restrict__ seq,
                                                      const unsigned char* __restrict__ mraw,
                                                      unsigned char* __restrict__ mout,
                                                      float* __restrict__ X, float* __restrict__ Q,
                                                      const float* __restrict__ g,
                                                      const float* __restrict__ be) {
    __shared__ int flags[2];
    __shared__ float ws[8];
    int row = blockIdx.x, tid = threadIdx.x;
    if (tid == 0) { flags[0] = 0; flags[1] = 0; }
    __syncthreads();
    for (int i = tid; i < 2048; i += 256) {
        if (mraw[i]) {
            if (i & 3) atomicOr(&flags[0], 1);
            else if (i & 4) atomicOr(&flags[1], 1);
        }
    }
    __syncthreads();
    int mode = flags[0] ? 0 : (flags[1] ? 1 : 2);
    unsigned char mrow = (mode == 0) ? mraw[row] : (mode == 1) ? mraw[row * 4] : mraw[row * 8];
    if (tid == 0) mout[row] = mrow ? 1 : 0;
    int idx = row * 256 + tid;
    int w = tid >> 6, lane = tid & 63;
    float v = mrow ? 0.f : seq[idx];
    X[idx] = v;
    float s = wave_sum(v);
    if (lane == 0) ws[w] = s;
    __syncthreads();
    float mean = (ws[0] + ws[1] + ws[2] + ws[3]) * (1.f / 256.f);
    float d = v - mean;
    float s2 = wave_sum(d * d);
    if (lane == 0) ws[4 + w] = s2;
    __syncthreads();
    float var = (ws[4] + ws[5] + ws[6] + ws[7]) * (1.f / 256.f);
    Q[idx] = d / sqrtf(var + 1e-8f) * g[tid] + be[tid];
}

// row layernorm over H=256
__global__ __launch_bounds__(256) void ln_kernel(const float* __restrict__ X, float* __restrict__ Y,
                                                 const float* __restrict__ g,
                                                 const float* __restrict__ be) {
    __shared__ float ws[8];
    int row = blockIdx.x, tid = threadIdx.x;
    int idx = row * 256 + tid;
    int w = tid >> 6, lane = tid & 63;
    float v = X[idx];
    float s = wave_sum(v);
    if (lane == 0) ws[w] = s;
    __syncthreads();
    float mean = (ws[0] + ws[1] + ws[2] + ws[3]) * (1.f / 256.f);
    float d = v - mean;
    float s2 = wave_sum(d * d);
    if (lane == 0) ws[4 + w] = s2;
    __syncthreads();
    float var = (ws[4] + ws[5] + ws[6] + ws[7]) * (1.f / 256.f);
    Y[idx] = d / sqrtf(var + 1e-8f) * g[tid] + be[tid];
}

// layernorm of (Xa + Xb) — fuses the outv split-K partial sum.
__global__ __launch_bounds__(256) void ln2sum_kernel(const float* __restrict__ Xa,
                                                     const float* __restrict__ Xb,
                                                     float* __restrict__ Y,
                                                     const float* __restrict__ g,
                                                     const float* __restrict__ be) {
    __shared__ float ws[8];
    int row = blockIdx.x, tid = threadIdx.x;
    int idx = row * 256 + tid;
    int w = tid >> 6, lane = tid & 63;
    float v = Xa[idx] + Xb[idx];
    float s = wave_sum(v);
    if (lane == 0) ws[w] = s;
    __syncthreads();
    float mean = (ws[0] + ws[1] + ws[2] + ws[3]) * (1.f / 256.f);
    float d = v - mean;
    float s2 = wave_sum(d * d);
    if (lane == 0) ws[4 + w] = s2;
    __syncthreads();
    float var = (ws[4] + ws[5] + ws[6] + ws[7]) * (1.f / 256.f);
    Y[idx] = d / sqrtf(var + 1e-8f) * g[tid] + be[tid];
}

struct GemmJob {
    const float* A; const float* W; const float* bias; const float* pos; float* C;
};

// Unified 32x32-tile GEMM, 2x2/thread, BK=32, register prefetch. grid.z picks job.
// epilogue: +bias (+pos[l]) (relu) (+res) (*keep)
__global__ __launch_bounds__(256) void gemm32_kernel(GemmJob j0, GemmJob j1, GemmJob j2,
                                                     const float* __restrict__ res,
                                                     const unsigned char* __restrict__ maskm,
                                                     int relu) {
    GemmJob J = (blockIdx.z == 0) ? j0 : (blockIdx.z == 1 ? j1 : j2);
    __shared__ float AsT[32][34];
    __shared__ float WsT[32][34];
    int tid = threadIdx.x;
    int n0 = blockIdx.x * 32, m0 = blockIdx.y * 32;
    int r = tid >> 4, c = tid & 15;
    int li = tid >> 3, lk = (tid & 7) * 4;
    const float* Ap = J.A + (m0 + li) * 256 + lk;
    const float* Wp = J.W + (n0 + li) * 256 + lk;
    float acc00 = 0, acc01 = 0, acc10 = 0, acc11 = 0;
    float4 av = *(const float4*)(Ap);
    float4 wv = *(const float4*)(Wp);
    for (int k0 = 0; k0 < 256; k0 += 32) {
        AsT[lk + 0][li] = av.x; AsT[lk + 1][li] = av.y; AsT[lk + 2][li] = av.z; AsT[lk + 3][li] = av.w;
        WsT[lk + 0][li] = wv.x; WsT[lk + 1][li] = wv.y; WsT[lk + 2][li] = wv.z; WsT[lk + 3][li] = wv.w;
        __syncthreads();
        if (k0 + 32 < 256) {
            av = *(const float4*)(Ap + k0 + 32);
            wv = *(const float4*)(Wp + k0 + 32);
        }
#pragma unroll
        for (int kk = 0; kk < 32; ++kk) {
            float2 a = *(const float2*)&AsT[kk][r * 2];
            float2 b = *(const float2*)&WsT[kk][c * 2];
            acc00 += a.x * b.x; acc01 += a.x * b.y;
            acc10 += a.y * b.x; acc11 += a.y * b.y;
        }
        __syncthreads();
    }
    float accs[2][2] = {{acc00, acc01}, {acc10, acc11}};
#pragma unroll
    for (int i = 0; i < 2; ++i) {
        int m = m0 + r * 2 + i;
#pragma unroll
        for (int jj = 0; jj < 2; ++jj) {
            int n = n0 + c * 2 + jj;
            float v = accs[i][jj] + J.bias[n];
            if (J.pos) v += J.pos[(m & 255) * 256 + n];
            if (relu) v = fmaxf(v, 0.f);
            if (res) v += res[m * 256 + n];
            if (maskm && maskm[m]) v = 0.f;
            J.C[m * 256 + n] = v;
        }
    }
}

// K1: T[qg][h][t] = sum_d Qb[qg][h*64+d] * tK[t][h*64+d].  64q x 64t tile, h = blockIdx.z.
__global__ __launch_bounds__(256) void qtk_kernel(const float* __restrict__ Qb,
                                                  const float* __restrict__ tK,
                                                  float* __restrict__ T) {
    __shared__ float QsT[32][68];
    __shared__ float TsT[32][68];
    int tid = threadIdx.x;
    int q0 = blockIdx.x * 64, t0 = blockIdx.y * 64, h = blockIdx.z;
    int r = tid >> 4, c = tid & 15;
    int li = tid >> 2, lk = (tid & 3) * 8;
    int tr = t0 + li; if (tr > 512) tr = 512;
    float acc[4][4] = {};
    for (int kc = 0; kc < 64; kc += 32) {
        float4 a0 = *(const float4*)(Qb + (q0 + li) * 256 + h * 64 + kc + lk);
        float4 a1 = *(const float4*)(Qb + (q0 + li) * 256 + h * 64 + kc + lk + 4);
        QsT[lk + 0][li] = a0.x; QsT[lk + 1][li] = a0.y; QsT[lk + 2][li] = a0.z; QsT[lk + 3][li] = a0.w;
        QsT[lk + 4][li] = a1.x; QsT[lk + 5][li] = a1.y; QsT[lk + 6][li] = a1.z; QsT[lk + 7][li] = a1.w;
        float4 b0 = *(const float4*)(tK + tr * 256 + h * 64 + kc + lk);
        float4 b1 = *(const float4*)(tK + tr * 256 + h * 64 + kc + lk + 4);
        TsT[lk + 0][li] = b0.x; TsT[lk + 1][li] = b0.y; TsT[lk + 2][li] = b0.z; TsT[lk + 3][li] = b0.w;
        TsT[lk + 4][li] = b1.x; TsT[lk + 5][li] = b1.y; TsT[lk + 6][li] = b1.z; TsT[lk + 7][li] = b1.w;
        __syncthreads();
#pragma unroll
        for (int kk = 0; kk < 32; ++kk) {
            float4 a = *(const float4*)&QsT[kk][r * 4];
            float4 bv = *(const float4*)&TsT[kk][c * 4];
            acc[0][0] += a.x * bv.x; acc[0][1] += a.x * bv.y; acc[0][2] += a.x * bv.z; acc[0][3] += a.x * bv.w;
            acc[1][0] += a.y * bv.x; acc[1][1] += a.y * bv.y; acc[1][2] += a.y * bv.z; acc[1][3] += a.y * bv.w;
            acc[2][0] += a.z * bv.x; acc[2][1] += a.z * bv.y; acc[2][2] += a.z * bv.z; acc[2][3] += a.z * bv.w;
            acc[3][0] += a.w * bv.x; acc[3][1] += a.w * bv.y; acc[3][2] += a.w * bv.z; acc[3][3] += a.w * bv.w;
        }
        __syncthreads();
    }
#pragma unroll
    for (int i = 0; i < 4; ++i)
#pragma unroll
        for (int j = 0; j < 4; ++j) {
            int t = t0 + c * 4 + j;
            if (t < 513) T[((size_t)(q0 + r * 4 + i) * 4 + h) * 513 + t] = acc[i][j];
        }
}

// K2: per (b,h,16q): S = Q@K^T + T-gather, mask, softmax, G-histogram. K streamed.
__global__ __launch_bounds__(256) void score_kernel(const float* __restrict__ Qb,
                                                    const float* __restrict__ KpB,
                                                    const float* __restrict__ T,
                                                    const int* __restrict__ tm,
                                                    const unsigned char* __restrict__ mask,
                                                    float* __restrict__ PG) {
    int tid = threadIdx.x;
    int q0 = blockIdx.x * 16;
    int bh = blockIdx.y, b = bh >> 2, h = bh & 3;
    __shared__ float Qs[16][68];
    __shared__ float Sl[16][264];
    __shared__ float Gl[4][544];
    __shared__ unsigned char mrow[16];
    {
        int li = tid >> 4, lk = tid & 15;
        *(float4*)&Qs[li][lk * 4] = *(const float4*)(Qb + (size_t)(b * 256 + q0 + li) * 256 + h * 64 + lk * 4);
    }
    if (tid < 16) mrow[tid] = mask[b * 256 + q0 + tid];
    __syncthreads();

    int k = tid;
    const float* krow = KpB + (size_t)((b << 8) + k) * 256 + h * 64;
    float acc[16];
#pragma unroll
    for (int qq = 0; qq < 16; ++qq) acc[qq] = 0.f;
#pragma unroll 4
    for (int d4 = 0; d4 < 16; ++d4) {
        float4 kv = *(const float4*)(krow + d4 * 4);
#pragma unroll
        for (int qq = 0; qq < 16; ++qq) {
            float4 q4 = *(const float4*)&Qs[qq][d4 * 4];
            acc[qq] += q4.x * kv.x + q4.y * kv.y + q4.z * kv.z + q4.w * kv.w;
        }
    }
    const int* tmcol = tm + (size_t)(b * 256 + q0) * 256 + k;
#pragma unroll
    for (int qq = 0; qq < 16; ++qq) {
        int qg = q0 + qq;
        int t = tmcol[qq * 256]; t = t < 0 ? 0 : (t > 512 ? 512 : t);
        float s = (acc[qq] + T[((size_t)(b * 256 + qg) * 4 + h) * 513 + t]) * 0.125f;
        if (k > qg || mrow[qq]) s = BIG_NEG_F;
        Sl[qq][k] = s;
    }
    __syncthreads();

    int w = tid >> 6, lane = tid & 63;
    float* pgB = PG + (size_t)bh * 256 * 800;
    for (int rr = 0; rr < 4; ++rr) {
        int qq = w * 4 + rr, qg = q0 + qq;
        float v0 = Sl[qq][lane], v1 = Sl[qq][lane + 64], v2 = Sl[qq][lane + 128], v3 = Sl[qq][lane + 192];
        float mx = wave_max(fmaxf(fmaxf(v0, v1), fmaxf(v2, v3)));
        float e0 = __expf(v0 - mx), e1 = __expf(v1 - mx), e2 = __expf(v2 - mx), e3 = __expf(v3 - mx);
        float inv = 1.f / wave_sum(e0 + e1 + e2 + e3);
        e0 *= inv; e1 *= inv; e2 *= inv; e3 *= inv;
        float* prow = pgB + (size_t)qg * 800;
        prow[lane] = e0; prow[lane + 64] = e1; prow[lane + 128] = e2; prow[lane + 192] = e3;
#pragma unroll
        for (int j = 0; j < 9; ++j) { int idx = lane + j * 64; if (idx < 544) Gl[w][idx] = 0.f; }
        const int* tq = tm + (size_t)(b * 256 + qg) * 256;
        {
            int ta = tq[lane], tb2 = tq[lane + 64], tc = tq[lane + 128], td = tq[lane + 192];
            ta = ta < 0 ? 0 : (ta > 512 ? 512 : ta);
            tb2 = tb2 < 0 ? 0 : (tb2 > 512 ? 512 : tb2);
            tc = tc < 0 ? 0 : (tc > 512 ? 512 : tc);
            td = td < 0 ? 0 : (td > 512 ? 512 : td);
            atomicAdd(&Gl[w][ta], e0);
            atomicAdd(&Gl[w][tb2], e1);
            atomicAdd(&Gl[w][tc], e2);
            atomicAdd(&Gl[w][td], e3);
        }
#pragma unroll
        for (int j = 0; j < 9; ++j) { int idx = lane + j * 64; if (idx < 544) prow[256 + idx] = Gl[w][idx]; }
    }
}

// K3: split-K GEMM. z=0: kc 0..400 (+qres) -> Xa;  z=1: kc 400..800 -> Xb.
// 32q x 64n tile, 2x4/thread. AsT stride 34 (2-way max on transpose writes).
__global__ __launch_bounds__(256) void outv_kernel(const float* __restrict__ PG,
                                                   const float* __restrict__ Vp,
                                                   const float* __restrict__ tV,
                                                   const float* __restrict__ qres,
                                                   float* __restrict__ Xa,
                                                   float* __restrict__ Xb) {
    int tid = threadIdx.x;
    int q0 = blockIdx.x * 32;
    int bh = blockIdx.y, b = bh >> 2, h = bh & 3;
    int kbeg = blockIdx.z * 400;
    __shared__ float AsT[32][34];   // [k][q]
    __shared__ float Bs[32][68];    // [k][n]
    int r = tid >> 4, c = tid & 15;
    int liA = tid >> 3, lkA = (tid & 7) * 4;
    int liB = tid >> 3, lkB = (tid & 7) * 8;
    const float* Abase = PG + (size_t)bh * 256 * 800 + (size_t)(q0 + liA) * 800 + kbeg + lkA;
    float acc[2][4] = {};
    for (int kc = 0; kc < 400; kc += 32) {
        float4 a4 = *(const float4*)(Abase + kc);
        AsT[lkA + 0][liA] = a4.x; AsT[lkA + 1][liA] = a4.y;
        AsT[lkA + 2][liA] = a4.z; AsT[lkA + 3][liA] = a4.w;
        int rrow = kbeg + kc + liB;
        float4 b0, b1;
        if (rrow < 256) {
            const float* p = Vp + (size_t)((b << 8) + rrow) * 256 + h * 64 + lkB;
            b0 = *(const float4*)p; b1 = *(const float4*)(p + 4);
        } else if (rrow < 769) {
            const float* p = tV + (size_t)(rrow - 256) * 256 + h * 64 + lkB;
            b0 = *(const float4*)p; b1 = *(const float4*)(p + 4);
        } else {
            b0 = make_float4(0.f, 0.f, 0.f, 0.f); b1 = b0;
        }
        *(float4*)&Bs[liB][lkB] = b0;
        *(float4*)&Bs[liB][lkB + 4] = b1;
        __syncthreads();
#pragma unroll
        for (int kk = 0; kk < 32; ++kk) {
            float2 a = *(const float2*)&AsT[kk][r * 2];
            float4 b4 = *(const float4*)&Bs[kk][c * 4];
            acc[0][0] += a.x * b4.x; acc[0][1] += a.x * b4.y; acc[0][2] += a.x * b4.z; acc[0][3] += a.x * b4.w;
            acc[1][0] += a.y * b4.x; acc[1][1] += a.y * b4.y; acc[1][2] += a.y * b4.z; acc[1][3] += a.y * b4.w;
        }
        __syncthreads();
    }
#pragma unroll
    for (int s = 0; s < 2; ++s) {
        int qg = b * 256 + q0 + r * 2 + s;
        int col = h * 64 + c * 4;
        float4 o;
        o.x = acc[s][0]; o.y = acc[s][1]; o.z = acc[s][2]; o.w = acc[s][3];
        if (blockIdx.z == 0) {
            float4 rv = *(const float4*)(qres + (size_t)qg * 256 + col);
            o.x += rv.x; o.y += rv.y; o.z += rv.z; o.w += rv.w;
            *(float4*)(Xa + (size_t)qg * 256 + col) = o;
        } else {
            *(float4*)(Xb + (size_t)qg * 256 + col) = o;
        }
    }
}

extern "C" void kernel_launch(void* const* d_in, const int* in_sizes, int n_in,
                              void* d_out, int out_size, void* d_ws, size_t ws_size,
                              hipStream_t stream) {
    const unsigned char* mask_raw = (const unsigned char*)d_in[0];
    const float* seq  = (const float*)d_in[1];
    const int*   tm   = (const int*)d_in[3];
    const float* Wq   = (const float*)d_in[5];
    const float* bq   = (const float*)d_in[6];
    const float* Wk   = (const float*)d_in[7];
    const float* bk   = (const float*)d_in[8];
    const float* Wv   = (const float*)d_in[9];
    const float* bv   = (const float*)d_in[10];
    const float* ln1g = (const float*)d_in[11];
    const float* ln1b = (const float*)d_in[12];
    const float* ln2g = (const float*)d_in[13];
    const float* ln2b = (const float*)d_in[14];
    const float* W1   = (const float*)d_in[15];
    const float* b1   = (const float*)d_in[16];
    const float* W2   = (const float*)d_in[17];
    const float* b2   = (const float*)d_in[18];
    const float* posK = (const float*)d_in[19];
    const float* posV = (const float*)d_in[20];
    const float* tK   = (const float*)d_in[21];
    const float* tV   = (const float*)d_in[22];
    const float* lnfg = (const float*)d_in[23];
    const float* lnfb = (const float*)d_in[24];

    const size_t NEL = 8 * 256 * 256;
    float* x   = (float*)d_ws;          // pre-attn x; then outv Xa; then FFN2 out
    float* q   = x   + NEL;             // ln1 output (attn residual)
    float* Qb  = q   + NEL;
    float* KpB = Qb  + NEL;
    float* VpB = KpB + NEL;
    float* x2  = VpB + NEL;
    float* hb  = x2  + NEL;
    unsigned char* mask = (unsigned char*)(hb + NEL);
    float* T  = hb + NEL + 1024;                        // [2048][4][513]
    float* PG = T + (size_t)2048 * 4 * 513;             // [32][256][800]
    float* xb = PG + (size_t)32 * 256 * 800;            // outv split-K partial

    dim3 gQKV(8, 64, 3);
    dim3 gFFN(8, 64, 1);
    dim3 gQTK(32, 9, 4);
    dim3 gSC(16, 32);
    dim3 gOV(8, 32, 2);

    prep_ln_kernel<<<2048, 256, 0, stream>>>(seq, mask_raw, mask, x, q, ln1g, ln1b);
    for (int blk = 0; blk < 2; ++blk) {
        int o1 = blk * 256, oW = blk * 256 * 256;
        GemmJob jq = {q, Wq + oW, bq + o1, nullptr, Qb};
        GemmJob jk = {x, Wk + oW, bk + o1, posK,    KpB};
        GemmJob jv = {x, Wv + oW, bv + o1, posV,    VpB};
        gemm32_kernel<<<gQKV, 256, 0, stream>>>(jq, jk, jv, nullptr, nullptr, 0);
        qtk_kernel<<<gQTK, 256, 0, stream>>>(Qb, tK, T);
        score_kernel<<<gSC, 256, 0, stream>>>(Qb, KpB, T, tm, mask, PG);
        outv_kernel<<<gOV, 256, 0, stream>>>(PG, VpB, tV, q, x, xb);
        ln2sum_kernel<<<2048, 256, 0, stream>>>(x, xb, x2, ln2g + o1, ln2b + o1);
        GemmJob jf1 = {x2, W1 + oW, b1 + o1, nullptr, hb};
        gemm32_kernel<<<gFFN, 256, 0, stream>>>(jf1, jf1, jf1, nullptr, nullptr, 1);
        GemmJob jf2 = {hb, W2 + oW, b2 + o1, nullptr, x};
        gemm32_kernel<<<gFFN, 256, 0, stream>>>(jf2, jf2, jf2, x2, mask, 0);
        if (blk == 0) ln_kernel<<<2048, 256, 0, stream>>>(x, q, ln1g + 256, ln1b + 256);
    }
    ln_kernel<<<2048, 256, 0, stream>>>(x, (float*)d_out, lnfg, lnfb);
}